// Round 15
// baseline (387.621 us; speedup 1.0000x reference)
//
#include <hip/hip_runtime.h>

// ResLSTM: B=4096, T=512, H=32.
// R22 = R21 (2-wave MFMA recurrence, raw-barrier exchange) + TWO INDEPENDENT
//   BATCH-GROUPS INTERLEAVED PER WAVE PAIR.
//   Block = 128 thr = 2 waves, handles 32 batches: group A = wbase..+15,
//   group B = +16..+31. Per time step: MFMA_A,GSTATE_A,write_A, MFMA_B,
//   GSTATE_B,write_B, ONE barrier, read_A, read_B. After the barrier only
//   read_A's ~120cy latency is exposed; read_B hides under A's ~340cy
//   compute; barrier/wave-skew amortizes 2x. Weights shared across groups
//   (only B8/c/h duplicate, ~+30 VGPR at waves_per_eu(1,1) budget 512).
//   128 blocks: half the CUs idle -- irrelevant, total time = one block's
//   serial wall (all blocks concurrent).
// R21 POST-MORTEM (183.7 us, 861 cy/step): busy 558, idle ~240 = the
//   ds_write->barrier->ds_read->MFMA chain; nothing else in a single
//   recurrence can fill it. Hence the second recurrence.
// History: R7 341. R11 297. R12 dot2 248. R14 230. R16 219 (VALU floor).
//   R18 K=16 305. R19 K=32 279. R20 2-wave 197. R21 raw barrier 183.7.
// Predict: ~680 cy/group-step -> 125-150 us; Occupancy ~2.9%; absmax
//   EXACTLY 0.0009765625. Failure >=175: groups serialized or spill
//   (check VGPR) -> disasm round.

static constexpr int T_LEN = 512;
static constexpr int H = 32;

typedef _Float16 h2   __attribute__((ext_vector_type(2)));
typedef __fp16   fp2  __attribute__((ext_vector_type(2)));   // cvt_pkrtz type
typedef _Float16 v8h  __attribute__((ext_vector_type(8)));
typedef float    v4f  __attribute__((ext_vector_type(4)));

// D = A(8 f16) x B(8 f16) + C(4 f32), 16x16x32 f16 MFMA (K=32).
__device__ __forceinline__ v4f MF32(v8h a, v8h b, v4f c) {
#if __has_builtin(__builtin_amdgcn_mfma_f32_16x16x32_f16)
    return __builtin_amdgcn_mfma_f32_16x16x32_f16(a, b, c, 0, 0, 0);
#else
    v4f d = c;
    asm("v_mfma_f32_16x16x32_f16 %0, %1, %2, %0" : "+v"(d) : "v"(a), "v"(b));
    return d;
#endif
}

__device__ __forceinline__ v8h mkB(uint4 w) {
    union { uint4 u; v8h v; } u;
    u.u = w; return u.v;
}

__global__ void
__attribute__((amdgpu_flat_work_group_size(128, 128), amdgpu_waves_per_eu(1, 1)))
reslstm_kernel(const float* __restrict__ x,
               const float* __restrict__ W_ih,
               const float* __restrict__ W_hh,
               const float* __restrict__ b_ih,
               const float* __restrict__ b_hh,
               const float* __restrict__ W_fc,
               const float* __restrict__ b_fc,
               float* __restrict__ out, int B)
{
    // x chunk: [row 0..15 = group A col c | row 16..31 = group B col c][t].
    __shared__ float xl[32][36];
    // h exchange: [group][parity][q][c][wave] 8B slots.
    __shared__ uint2 hx[2][2][4][16][2];
    __shared__ float osum[2][2][16];     // [group][wave][c]

    const int tid  = threadIdx.x;
    const int lane = tid & 63;
    const int wv   = tid >> 6;           // wave 0: units 0-15, wave 1: 16-31
    const int c    = lane & 15;          // batch col (0..15)
    const int q    = lane >> 4;          // row quad  (0..3)

    const int wbase = blockIdx.x << 5;   // 32 batches per block (2 groups)
    if (wbase >= B) return;              // block-uniform guard
    const int bbA = wbase + c;
    const int bbB = wbase + 16 + c;

    constexpr float NL2E  = -1.4426950408889634f;   // -log2(e)
    constexpr float N2L2E = 2.0f * NL2E;

    // A fragments: tile t = 2k + wv (gate k of unit-half wv). Shared by
    // both groups. Prescale: g gate (k==2) by 2*-log2(e), else -log2(e).
    v8h A8[4];
    v4f wih[4], bsb[4];
    #pragma unroll
    for (int k = 0; k < 4; ++k) {
        const int   t  = 2 * k + wv;
        const float sc = (k == 2) ? N2L2E : NL2E;
        const float4 w1 = *reinterpret_cast<const float4*>(
            W_hh + (16 * t + c) * H + 4 * q);
        const float4 w2 = *reinterpret_cast<const float4*>(
            W_hh + (16 * t + c) * H + 16 + 4 * q);
        A8[k][0] = (_Float16)(w1.x * sc); A8[k][1] = (_Float16)(w1.y * sc);
        A8[k][2] = (_Float16)(w1.z * sc); A8[k][3] = (_Float16)(w1.w * sc);
        A8[k][4] = (_Float16)(w2.x * sc); A8[k][5] = (_Float16)(w2.y * sc);
        A8[k][6] = (_Float16)(w2.z * sc); A8[k][7] = (_Float16)(w2.w * sc);
        const int r0 = 16 * t + 4 * q;
        const float4 wi = *reinterpret_cast<const float4*>(W_ih + r0);
        const float4 bi = *reinterpret_cast<const float4*>(b_ih + r0);
        const float4 bh = *reinterpret_cast<const float4*>(b_hh + r0);
        wih[k][0] = wi.x * sc; wih[k][1] = wi.y * sc;
        wih[k][2] = wi.z * sc; wih[k][3] = wi.w * sc;
        bsb[k][0] = (bi.x + bh.x) * sc; bsb[k][1] = (bi.y + bh.y) * sc;
        bsb[k][2] = (bi.z + bh.z) * sc; bsb[k][3] = (bi.w + bh.w) * sc;
    }

    // Per-group state: this wave's 4 units (16wv + 4q + m).
    float cA0 = 0.f, cA1 = 0.f, cA2 = 0.f, cA3 = 0.f;
    float hA0 = 0.f, hA1 = 0.f, hA2 = 0.f, hA3 = 0.f;
    float cB0 = 0.f, cB1 = 0.f, cB2 = 0.f, cB3 = 0.f;
    float hB0 = 0.f, hB1 = 0.f, hB2 = 0.f, hB3 = 0.f;
    v8h B8A = mkB(uint4{0u, 0u, 0u, 0u});         // h(0) = 0
    v8h B8B = B8A;

// Light pins once per chunk (R6 lesson: asm outputs can't be rematerialized
// from memory -> weights stay VGPR-resident; R13: placement neutral).
#define PINALL()                                                              \
    asm volatile("" : "+v"(A8[0]), "+v"(A8[1]), "+v"(A8[2]), "+v"(A8[3]));    \
    asm volatile("" : "+v"(wih[0]), "+v"(wih[1]), "+v"(wih[2]), "+v"(wih[3]), \
                      "+v"(bsb[0]), "+v"(bsb[1]), "+v"(bsb[2]), "+v"(bsb[3]))

// R14 exp2 gate math (accums prescaled by -log2(e)):
//   c' = [c*Di*Dg + (1-Eg)*Df] * rcp(Df*Di*Dg);  h = (1-Ec) * rcp(Do*Dc).
#define GSTATE(AI, AF, AG, AO, CC, HH) do {                                   \
    const float Ei = __builtin_amdgcn_exp2f(AI);                              \
    const float Ef = __builtin_amdgcn_exp2f(AF);                              \
    const float Eg = __builtin_amdgcn_exp2f(AG);                              \
    const float Eo = __builtin_amdgcn_exp2f(AO);                              \
    const float Di = 1.0f + Ei, Df = 1.0f + Ef;                               \
    const float Dg = 1.0f + Eg, Do_ = 1.0f + Eo;                              \
    const float P  = Di * Dg;                                                 \
    const float t_ = (1.0f - Eg) * Df;                                        \
    const float u_ = __builtin_fmaf(CC, P, t_);                               \
    const float Rc = __builtin_amdgcn_rcpf(Df * P);                           \
    CC = u_ * Rc;                                                             \
    const float Ec = __builtin_amdgcn_exp2f(CC * N2L2E);                      \
    const float Dc = 1.0f + Ec;                                               \
    const float Rh = __builtin_amdgcn_rcpf(Do_ * Dc);                         \
    HH = (1.0f - Ec) * Rh;                                                    \
} while (0)

// Compute half-step for one group: 4 MFMA -> 4 GSTATE -> 2 b32 h-writes.
#define STEPG(XT, PAR, GRP, B8R, C0, C1, C2, C3, H0, H1, H2, H3) do {         \
    const float xt = (XT);                                                    \
    v4f acc[4];                                                               \
    _Pragma("unroll")                                                         \
    for (int k = 0; k < 4; ++k) acc[k] = bsb[k] + wih[k] * xt;                \
    _Pragma("unroll")                                                         \
    for (int k = 0; k < 4; ++k) acc[k] = MF32(A8[k], B8R, acc[k]);            \
    unsigned int* slot =                                                      \
        reinterpret_cast<unsigned int*>(&hx[GRP][PAR][q][c][wv]);             \
    GSTATE(acc[0][0], acc[1][0], acc[2][0], acc[3][0], C0, H0);               \
    GSTATE(acc[0][1], acc[1][1], acc[2][1], acc[3][1], C1, H1);               \
    slot[0] = __builtin_bit_cast(unsigned int,                                \
                  __builtin_amdgcn_cvt_pkrtz(H0, H1));                        \
    GSTATE(acc[0][2], acc[1][2], acc[2][2], acc[3][2], C2, H2);               \
    GSTATE(acc[0][3], acc[1][3], acc[2][3], acc[3][3], C3, H3);               \
    slot[1] = __builtin_bit_cast(unsigned int,                                \
                  __builtin_amdgcn_cvt_pkrtz(H2, H3));                        \
} while (0)

// Full time step: both groups, ONE barrier. Race proof as R20/R21 (per
// group, parity-double-buffered; barrier(t+1) orders write(t+2) after
// read(t)).
#define STEP2(XTA, XTB, PAR) do {                                             \
    STEPG(XTA, PAR, 0, B8A, cA0, cA1, cA2, cA3, hA0, hA1, hA2, hA3);          \
    STEPG(XTB, PAR, 1, B8B, cB0, cB1, cB2, cB3, hB0, hB1, hB2, hB3);          \
    asm volatile("s_waitcnt lgkmcnt(0)\n\ts_barrier" ::: "memory");           \
    B8A = mkB(*reinterpret_cast<const uint4*>(&hx[0][PAR][q][c][0]));         \
    B8B = mkB(*reinterpret_cast<const uint4*>(&hx[1][PAR][q][c][0]));         \
} while (0)

    // x staging: thread tid owns row r=tid>>3 (0..15) of BOTH groups,
    // cols colb..colb+3 of the 32-step chunk.
    const int r    = tid >> 3;
    const int colb = (tid & 7) << 2;
    const float* xsrcA = x + (size_t)(wbase + r) * T_LEN + colb;
    const float* xsrcB = x + (size_t)(wbase + 16 + r) * T_LEN + colb;
    float4 xpA = *reinterpret_cast<const float4*>(xsrcA);
    float4 xpB = *reinterpret_cast<const float4*>(xsrcB);

    for (int tc = 0; tc < T_LEN / 32; ++tc) {
        PINALL();
        *reinterpret_cast<float4*>(&xl[r][colb])      = xpA;
        *reinterpret_cast<float4*>(&xl[16 + r][colb]) = xpB;
        __syncthreads();                  // stage visible to both waves
        if (tc + 1 < T_LEN / 32) {
            xpA = *reinterpret_cast<const float4*>(xsrcA + (tc + 1) * 32);
            xpB = *reinterpret_cast<const float4*>(xsrcB + (tc + 1) * 32);
        }
        const float4* xqA = reinterpret_cast<const float4*>(&xl[c][0]);
        const float4* xqB = reinterpret_cast<const float4*>(&xl[16 + c][0]);
        for (int t4 = 0; t4 < 8; ++t4) {
            const float4 xvA = xqA[t4];   // 4 steps of x in regs, per group
            const float4 xvB = xqB[t4];
            STEP2(xvA.x, xvB.x, 0);
            STEP2(xvA.y, xvB.y, 1);
            STEP2(xvA.z, xvB.z, 0);
            STEP2(xvA.w, xvB.w, 1);
        }
    }
#undef STEP2
#undef STEPG
#undef GSTATE
#undef PINALL

    // out = sum_u h[u]*W_fc[u] + b_fc per group. This wave: units 16wv+4q+m.
    const int u0 = 16 * wv + 4 * q;
    const float w0 = W_fc[u0],     w1 = W_fc[u0 + 1];
    const float w2 = W_fc[u0 + 2], w3 = W_fc[u0 + 3];
    float vA = hA0 * w0 + hA1 * w1 + hA2 * w2 + hA3 * w3;
    float vB = hB0 * w0 + hB1 * w1 + hB2 * w2 + hB3 * w3;
    vA += __shfl_xor(vA, 16); vA += __shfl_xor(vA, 32);
    vB += __shfl_xor(vB, 16); vB += __shfl_xor(vB, 32);
    if (q == 0) { osum[0][wv][c] = vA; osum[1][wv][c] = vB; }
    __syncthreads();
    if (wv == 0 && q == 0) {
        if (bbA < B) out[bbA] = osum[0][0][c] + osum[0][1][c] + b_fc[0];
        if (bbB < B) out[bbB] = osum[1][0][c] + osum[1][1][c] + b_fc[0];
    }
}

extern "C" void kernel_launch(void* const* d_in, const int* in_sizes, int n_in,
                              void* d_out, int out_size, void* d_ws, size_t ws_size,
                              hipStream_t stream) {
    const float* x    = (const float*)d_in[0];
    const float* W_ih = (const float*)d_in[1];
    const float* W_hh = (const float*)d_in[2];
    const float* b_ih = (const float*)d_in[3];
    const float* b_hh = (const float*)d_in[4];
    const float* W_fc = (const float*)d_in[5];
    const float* b_fc = (const float*)d_in[6];
    float* out = (float*)d_out;
    const int B = in_sizes[0] / T_LEN;        // 4096
    dim3 block(128);                          // 2 waves = 2 x 16 batches
    dim3 grid((B + 31) / 32);                 // 128 blocks
    reslstm_kernel<<<grid, block, 0, stream>>>(x, W_ih, W_hh, b_ih, b_hh,
                                               W_fc, b_fc, out, B);
}

// Round 16
// 246.374 us; speedup vs baseline: 1.5733x; 1.5733x over previous
//
#include <hip/hip_runtime.h>

// ResLSTM: B=4096, T=512, H=32.
// R23 STRUCTURE: MFMA recurrence, FOUR cooperating waves per 16 batches.
//   Block = 256 thr = 4 waves; wave w owns units 8w..8w+7 and computes
//   tile0 = [i rows 8w..+7 || f rows] and tile1 = [g || o] -> 2 MFMA K=32
//   + 2 GSTATE per wave (half of R21's per-wave work).
//   Gate completion is INTRA-WAVE: lane quads q<2 hold i,g; q>=2 hold f,o
//   of the same units -> 8 shfl_xor(.,32) + cndmask selects (no barrier).
//   h-exchange: one parity-buffered b32 write + barrier + b128 read; a
//   slot permutation keeps each lane's read = its B-fragment k-slots
//   {4q+m, 16+4q+m} contiguous.
// R22 POST-MORTEM (338 us): arithmetic error -- 2 groups in the SAME wave
//   makes wall = 2xbusy + stall; fewer blocks buys nothing (all blocks
//   already concurrent). Issue-bound, not latency-bound. Reverted.
// R21 ledger (183.7 us, 861 cy/step): busy 558 (~200 MFMA-active, ~240
//   GSTATE, ~120 misc) + ~300 exchange stall. R23 halves busy per wave.
// History: R7 341. R11 297. R12 dot2 248. R14 230. R16 219 (VALU floor).
//   R18 K=16 305. R19 K=32 279. R20 2-wave 197. R21 raw barrier 183.7.
//   R22 two-groups-per-wave 338 (reverted).
// Predict: 110-145 us; VALUBusy(CU) 45-60%; MfmaUtil ~3.5-4; Occupancy
//   ~11%; absmax EXACTLY 0.0009765625 (preacts/GSTATE inputs bitwise
//   identical to R21). Failure >=170: barrier skew + shuffle cost ->
//   revert R21, near-floor.

static constexpr int T_LEN = 512;
static constexpr int H = 32;

typedef _Float16 h2   __attribute__((ext_vector_type(2)));
typedef __fp16   fp2  __attribute__((ext_vector_type(2)));   // cvt_pkrtz type
typedef _Float16 v8h  __attribute__((ext_vector_type(8)));
typedef float    v4f  __attribute__((ext_vector_type(4)));

// D = A(8 f16) x B(8 f16) + C(4 f32), 16x16x32 f16 MFMA (K=32).
__device__ __forceinline__ v4f MF32(v8h a, v8h b, v4f c) {
#if __has_builtin(__builtin_amdgcn_mfma_f32_16x16x32_f16)
    return __builtin_amdgcn_mfma_f32_16x16x32_f16(a, b, c, 0, 0, 0);
#else
    v4f d = c;
    asm("v_mfma_f32_16x16x32_f16 %0, %1, %2, %0" : "+v"(d) : "v"(a), "v"(b));
    return d;
#endif
}

__device__ __forceinline__ v8h mkB(uint4 w) {
    union { uint4 u; v8h v; } u;
    u.u = w; return u.v;
}

__global__ void
__attribute__((amdgpu_flat_work_group_size(256, 256), amdgpu_waves_per_eu(1, 1)))
reslstm_kernel(const float* __restrict__ x,
               const float* __restrict__ W_ih,
               const float* __restrict__ W_hh,
               const float* __restrict__ b_ih,
               const float* __restrict__ b_hh,
               const float* __restrict__ W_fc,
               const float* __restrict__ b_fc,
               float* __restrict__ out, int B)
{
    // x chunk: [batch-col][t], pad 36.
    __shared__ float xl[16][36];
    // h exchange, parity-buffered: [buf][c][20 uint] (80B rows, 16B-aligned
    // b128 reads at +q*16). Slot s of batch c = h-pair per the permutation
    // below; reader (c,q) reads slots 4q..4q+3 = units {4q..4q+3,16+4q..+3}.
    __shared__ unsigned int hxu[2][16][20];
    __shared__ float osum[4][16];

    const int tid  = threadIdx.x;
    const int lane = tid & 63;
    const int wv   = tid >> 6;           // wave w: units 8w..8w+7
    const int c    = lane & 15;          // batch col (0..15)
    const int q    = lane >> 4;          // row quad  (0..3)
    const bool hiq = (lane & 32) != 0;   // q >= 2

    const int wbase = blockIdx.x << 4;   // 16 batches per block
    if (wbase >= B) return;              // block-uniform guard
    const int bb = wbase + c;

    constexpr float NL2E  = -1.4426950408889634f;   // -log2(e)
    constexpr float N2L2E = 2.0f * NL2E;

    // This wave's two A tiles (rows keyed by lane's c):
    //   tile0 row r = (r<8) ? i-row 8wv+r       : f-row 32+8wv+r-8   (NL2E)
    //   tile1 row r = (r<8) ? g-row 64+8wv+r x2 : o-row 96+8wv+r-8   (NL2E)
    const int grow0 = (c < 8) ? (8 * wv + c) : (32 + 8 * wv + c - 8);
    const int grow1 = (c < 8) ? (64 + 8 * wv + c) : (96 + 8 * wv + c - 8);
    const float s0 = NL2E;
    const float s1 = (c < 8) ? N2L2E : NL2E;

    v8h A80, A81;
    {
        const float4 w1 = *reinterpret_cast<const float4*>(W_hh + grow0 * H + 4 * q);
        const float4 w2 = *reinterpret_cast<const float4*>(W_hh + grow0 * H + 16 + 4 * q);
        A80[0] = (_Float16)(w1.x * s0); A80[1] = (_Float16)(w1.y * s0);
        A80[2] = (_Float16)(w1.z * s0); A80[3] = (_Float16)(w1.w * s0);
        A80[4] = (_Float16)(w2.x * s0); A80[5] = (_Float16)(w2.y * s0);
        A80[6] = (_Float16)(w2.z * s0); A80[7] = (_Float16)(w2.w * s0);
        const float4 w3 = *reinterpret_cast<const float4*>(W_hh + grow1 * H + 4 * q);
        const float4 w4 = *reinterpret_cast<const float4*>(W_hh + grow1 * H + 16 + 4 * q);
        A81[0] = (_Float16)(w3.x * s1); A81[1] = (_Float16)(w3.y * s1);
        A81[2] = (_Float16)(w3.z * s1); A81[3] = (_Float16)(w3.w * s1);
        A81[4] = (_Float16)(w4.x * s1); A81[5] = (_Float16)(w4.y * s1);
        A81[6] = (_Float16)(w4.z * s1); A81[7] = (_Float16)(w4.w * s1);
    }

    // xproj consts, keyed by C rows 4q+m of each tile.
    v4f wih0, bsb0, wih1, bsb1;
    #pragma unroll
    for (int m = 0; m < 4; ++m) {
        const int rr = 4 * q + m;
        const int r0 = (rr < 8) ? (8 * wv + rr) : (32 + 8 * wv + rr - 8);
        const int r1 = (rr < 8) ? (64 + 8 * wv + rr) : (96 + 8 * wv + rr - 8);
        const float sc1 = (rr < 8) ? N2L2E : NL2E;
        wih0[m] = W_ih[r0] * NL2E;
        bsb0[m] = (b_ih[r0] + b_hh[r0]) * NL2E;
        wih1[m] = W_ih[r1] * sc1;
        bsb1[m] = (b_ih[r1] + b_hh[r1]) * sc1;
    }

    // This lane's 2 units: u0 = 8wv + (q&1)*4 + (q>>1)*2, pair p = u0/2,
    // LDS slot via permutation (reader (c,q') slots 4q'..+3 = pairs
    // {2q',2q'+1,8+2q',8+2q'+1}).
    const int u0 = 8 * wv + ((q & 1) << 2) + ((q >> 1) << 1);
    const int p  = u0 >> 1;
    const int slot = (p < 8) ? (((p >> 1) << 2) | (p & 1))
                             : ((((p - 8) >> 1) << 2) | 2 | (p & 1));

    float csa = 0.f, csb = 0.f, hva = 0.f, hvb = 0.f;
    v8h B8 = mkB(uint4{0u, 0u, 0u, 0u});          // h(0) = 0

// Light pins once per chunk (R6 lesson: asm outputs can't be rematerialized
// from memory; R13: placement neutral).
#define PINALL()                                                              \
    asm volatile("" : "+v"(A80), "+v"(A81));                                  \
    asm volatile("" : "+v"(wih0), "+v"(wih1), "+v"(bsb0), "+v"(bsb1))

// R14 exp2 gate math (accums prescaled by -log2(e)):
//   c' = [c*Di*Dg + (1-Eg)*Df] * rcp(Df*Di*Dg);  h = (1-Ec) * rcp(Do*Dc).
#define GSTATE(AI, AF, AG, AO, CC, HH) do {                                   \
    const float Ei = __builtin_amdgcn_exp2f(AI);                              \
    const float Ef = __builtin_amdgcn_exp2f(AF);                              \
    const float Eg = __builtin_amdgcn_exp2f(AG);                              \
    const float Eo = __builtin_amdgcn_exp2f(AO);                              \
    const float Di = 1.0f + Ei, Df = 1.0f + Ef;                               \
    const float Dg = 1.0f + Eg, Do_ = 1.0f + Eo;                              \
    const float P  = Di * Dg;                                                 \
    const float t_ = (1.0f - Eg) * Df;                                        \
    const float u_ = __builtin_fmaf(CC, P, t_);                               \
    const float Rc = __builtin_amdgcn_rcpf(Df * P);                           \
    CC = u_ * Rc;                                                             \
    const float Ec = __builtin_amdgcn_exp2f(CC * N2L2E);                      \
    const float Dc = 1.0f + Ec;                                               \
    const float Rh = __builtin_amdgcn_rcpf(Do_ * Dc);                         \
    HH = (1.0f - Ec) * Rh;                                                    \
} while (0)

// One time step. 2 MFMA -> 8 shfl + selects (gate completion) -> 2 GSTATE
// -> 1 b32 h-write -> raw barrier -> b128 read.
// Lanes q<2 own units with m=j (j=0,1); q>=2 own m=2+j; partner lane
// (xor 32) supplies the complementary gates.
#define STEP(XT, PAR) do {                                                    \
    const float xt = (XT);                                                    \
    v4f a0 = bsb0 + wih0 * xt;                                                \
    v4f a1 = bsb1 + wih1 * xt;                                                \
    a0 = MF32(A80, B8, a0);                                                   \
    a1 = MF32(A81, B8, a1);                                                   \
    const float r00 = __shfl_xor(a0[0], 32), r01 = __shfl_xor(a0[1], 32);     \
    const float r02 = __shfl_xor(a0[2], 32), r03 = __shfl_xor(a0[3], 32);     \
    const float r10 = __shfl_xor(a1[0], 32), r11 = __shfl_xor(a1[1], 32);     \
    const float r12 = __shfl_xor(a1[2], 32), r13 = __shfl_xor(a1[3], 32);     \
    const float AI0 = hiq ? r02 : a0[0];                                      \
    const float AF0 = hiq ? a0[2] : r00;                                      \
    const float AG0 = hiq ? r12 : a1[0];                                      \
    const float AO0 = hiq ? a1[2] : r10;                                      \
    const float AI1 = hiq ? r03 : a0[1];                                      \
    const float AF1 = hiq ? a0[3] : r01;                                      \
    const float AG1 = hiq ? r13 : a1[1];                                      \
    const float AO1 = hiq ? a1[3] : r11;                                      \
    GSTATE(AI0, AF0, AG0, AO0, csa, hva);                                     \
    GSTATE(AI1, AF1, AG1, AO1, csb, hvb);                                     \
    hxu[PAR][c][slot] = __builtin_bit_cast(unsigned int,                      \
                            __builtin_amdgcn_cvt_pkrtz(hva, hvb));            \
    asm volatile("s_waitcnt lgkmcnt(0)\n\ts_barrier" ::: "memory");           \
    B8 = mkB(*reinterpret_cast<const uint4*>(&hxu[PAR][c][q << 2]));          \
} while (0)

    // x staging: threads 0-127 stage the 16x32 chunk (as R21); waves 2,3 skip.
    const int r    = tid >> 3;
    const int colb = (tid & 7) << 2;
    const float* xsrc = x + (size_t)(wbase + (r & 15)) * T_LEN + colb;
    float4 xA;
    if (tid < 128) xA = *reinterpret_cast<const float4*>(xsrc);

    for (int tc = 0; tc < T_LEN / 32; ++tc) {
        PINALL();
        if (tid < 128)
            *reinterpret_cast<float4*>(&xl[r][colb]) = xA;
        __syncthreads();                  // stage visible to all 4 waves
        if (tid < 128 && tc + 1 < T_LEN / 32)
            xA = *reinterpret_cast<const float4*>(xsrc + (tc + 1) * 32);
        const float4* xq4c = reinterpret_cast<const float4*>(&xl[c][0]);
        #pragma unroll 2
        for (int t4 = 0; t4 < 8; ++t4) {
            const float4 xv = xq4c[t4];   // 4 steps of x in regs
            STEP(xv.x, 0);
            STEP(xv.y, 1);
            STEP(xv.z, 0);
            STEP(xv.w, 1);
        }
    }
#undef STEP
#undef GSTATE
#undef PINALL

    // out[bb] = sum_u h[u]*W_fc[u] + b_fc. This lane: units u0, u0+1.
    float val = hva * W_fc[u0] + hvb * W_fc[u0 + 1];
    val += __shfl_xor(val, 16);
    val += __shfl_xor(val, 32);
    if (q == 0) osum[wv][c] = val;
    __syncthreads();
    if (wv == 0 && q == 0 && bb < B)
        out[bb] = osum[0][c] + osum[1][c] + osum[2][c] + osum[3][c] + b_fc[0];
}

extern "C" void kernel_launch(void* const* d_in, const int* in_sizes, int n_in,
                              void* d_out, int out_size, void* d_ws, size_t ws_size,
                              hipStream_t stream) {
    const float* x    = (const float*)d_in[0];
    const float* W_ih = (const float*)d_in[1];
    const float* W_hh = (const float*)d_in[2];
    const float* b_ih = (const float*)d_in[3];
    const float* b_hh = (const float*)d_in[4];
    const float* W_fc = (const float*)d_in[5];
    const float* b_fc = (const float*)d_in[6];
    float* out = (float*)d_out;
    const int B = in_sizes[0] / T_LEN;        // 4096
    dim3 block(256);                          // 4 waves = 16 batch elements
    dim3 grid((B + 15) / 16);                 // 256 blocks -> 4 SIMDs/CU
    reslstm_kernel<<<grid, block, 0, stream>>>(x, W_ih, W_hh, b_ih, b_hh,
                                               W_fc, b_fc, out, B);
}